// Round 8
// baseline (1319.251 us; speedup 1.0000x reference)
//
#include <hip/hip_runtime.h>
#include <math.h>

// PQLayer forward, MI355X — R8: single fused kernel.
//   x: (B,512) fp32   C: (64,256,8) fp32
//   out0 x_hat (B,512) = C[m,k*,:]   out1 codes (B,64,256) = one_hot(k*)
//
// History: R4=R7=1203us regardless of K1 micro-structure; R5 bisection algebra
// => F (harness poison tax) >= 758us, addressable t1+t2 in [313,445]us.
// R8 fuses: kills one launch + bestk global round-trip + inter-kernel
// serialization. Block = 64 b-rows => codes slab is one contiguous 4 MB run.
//   Phase 1: wave w -> m in [8w,8w+8), lane = b. m wave-uniform (R4 pattern;
//            R6 proved breaking this thrashes L1). np-exact packed v4f tree.
//            bestk -> 4 KB LDS [m][b].
//   Phase 2: xhat coalesced; codes slab swept linearly, 512 float4/thread,
//            (row,m) wave-uniform per step -> one broadcast ds_read_u8/step.

#define B_SZ   16384
#define FEAT   512
#define M_SZ   64
#define K_SZ   256
#define D_SZ   8

typedef float v4f __attribute__((ext_vector_type(4)));

// 256 blocks x 512 threads (8 waves). Block owns b-rows [64*blk, 64*blk+64).
__global__ __launch_bounds__(512) void pq_fused(
    const float* __restrict__ x,
    const float* __restrict__ C,
    float* __restrict__ xhat,
    float* __restrict__ codes)
{
#pragma clang fp contract(off)   // np einsum: separate product roundings, no FMA

    const int t    = threadIdx.x;        // 0..511
    const int w    = t >> 6;             // wave 0..7
    const int lane = t & 63;
    const int b0   = blockIdx.x << 6;    // first of 64 rows
    const int b    = b0 + lane;          // phase-1 row for this lane

    __shared__ unsigned char lbk[M_SZ * 64];   // [m][b_local], 4 KB

    // ---------------- Phase 1: argmax for m in [8w, 8w+8), lane = b ----------------
    {
        const float* xrow = x + (size_t)b * FEAT;
#pragma unroll
        for (int j = 0; j < 8; ++j) {
            const int m = (w << 3) | j;                 // wave-uniform
            const v4f* xp = (const v4f*)(xrow + m * D_SZ);
            const v4f xa = xp[0];                       // (x0..x3)
            const v4f xb = xp[1];                       // (x4..x7)
            const float* __restrict__ Cm = C + (size_t)m * (K_SZ * D_SZ);

            float best  = -INFINITY;
            int   bestk = 0;
#pragma unroll 8
            for (int k = 0; k < K_SZ; ++k) {
                const v4f* cr = (const v4f*)(Cm + k * D_SZ);  // uniform -> s_load
                v4f P = xa * cr[0];               // (s0..s3), halves round separately
                v4f Q = xb * cr[1];               // (s4..s7)
                v4f T = P + Q;                    // (t0..t3)
                float dot = (T.x + T.y) + (T.z + T.w);  // np tree, exact order
                if (dot > best) { best = dot; bestk = k; }  // strict >: first max
            }
            lbk[(m << 6) | lane] = (unsigned char)bestk;
        }
    }

    __syncthreads();

    // ---------------- Phase 2a: xhat (block's 128 KB), coalesced ----------------
    // i2 = t + 512*jj: m = lane (const), b_local = w + 8*jj.
#pragma unroll
    for (int jj = 0; jj < 8; ++jj) {
        const int bl = w + (jj << 3);
        const int kb = (int)lbk[(lane << 6) | bl];
        const float* cw = C + ((size_t)lane * K_SZ + kb) * D_SZ;
        const float4 h0 = ((const float4*)cw)[0];
        const float4 h1 = ((const float4*)cw)[1];
        float* xh = xhat + (size_t)(b0 + bl) * FEAT + lane * D_SZ;
        ((float4*)xh)[0] = h0;
        ((float4*)xh)[1] = h1;
    }

    // ---------------- Phase 2b: codes slab, linear 4 MB stream ----------------
    // float4 index i = t + 512*j: i>>6 = w + 8j (exact), so
    //   m   = (w + 8j) & 63   (wave-uniform)
    //   row = (w + 8j) >> 6   (wave-uniform)
    //   k-offset of this float4 = 4*lane (constant per thread)
    const int lane4 = lane << 2;
    float4* const slab = (float4*)(codes + (size_t)b0 * (M_SZ * K_SZ));

#pragma unroll 4
    for (int j = 0; j < 512; ++j) {
        const int g   = w + (j << 3);
        const int mj  = g & 63;
        const int row = g >> 6;
        const int kk  = (int)lbk[(mj << 6) | row];   // broadcast ds_read_u8
        float4 v;
        v.x = (kk == lane4 + 0) ? 1.0f : 0.0f;
        v.y = (kk == lane4 + 1) ? 1.0f : 0.0f;
        v.z = (kk == lane4 + 2) ? 1.0f : 0.0f;
        v.w = (kk == lane4 + 3) ? 1.0f : 0.0f;
        slab[t + (j << 9)] = v;
    }
}

extern "C" void kernel_launch(void* const* d_in, const int* in_sizes, int n_in,
                              void* d_out, int out_size, void* d_ws, size_t ws_size,
                              hipStream_t stream)
{
    const float* x = (const float*)d_in[0];
    const float* C = (const float*)d_in[1];
    float* xhat  = (float*)d_out;                           // (B, 512)
    float* codes = (float*)d_out + (size_t)B_SZ * FEAT;     // (B, 64, 256)

    hipLaunchKernelGGL(pq_fused, dim3(256), dim3(512), 0, stream, x, C, xhat, codes);
}